// Round 1
// baseline (693.025 us; speedup 1.0000x reference)
//
#include <hip/hip_runtime.h>

// Problem constants (match reference)
#define B_N 2048
#define C_N 64
#define D_N 1024
// K_ACTIVE=4, N_POS=12, N_NEG_PER=20
#define MARGIN_C 0.15f
#define INV_TEMP (1.0f / 0.07f)

__global__ void zero_out_kernel(float* __restrict__ out) {
    if (threadIdx.x == 0) out[0] = 0.0f;
}

__device__ __forceinline__ float wred(float v) {
#pragma unroll
    for (int off = 32; off > 0; off >>= 1) v += __shfl_xor(v, off, 64);
    return v;
}

__global__ __launch_bounds__(256, 4)
void loss_kernel(const float* __restrict__ pred,
                 const int*   __restrict__ lab,
                 const float* __restrict__ emb,
                 const float* __restrict__ cpos,
                 const float* __restrict__ conn,
                 float* __restrict__ out)
{
    __shared__ float s_p[64];
    __shared__ int   s_lab[64];
    __shared__ int   s_act[4];
    __shared__ int   s_inact[60];
    __shared__ float s_dots[64][4];   // dots[c][j] = dot(emb_c, emb_act_j) raw
    __shared__ float s_nsq[64];       // squared norms
    __shared__ float s_pos[192];      // 64 x 3 channel positions
    __shared__ float s_dist[64 * 64]; // pairwise distances
    __shared__ float s_part[6];

    const int tid  = threadIdx.x;
    const int w    = tid >> 6;
    const int lane = tid & 63;
    const int b    = blockIdx.x;

    // ---- stage small per-row data ----
    if (tid < 64) {
        s_p[tid]   = pred[b * 64 + tid];
        s_lab[tid] = lab[b * 64 + tid];
    } else if (tid < 64 + 192) {
        s_pos[tid - 64] = cpos[tid - 64];
    }
    __syncthreads();

    // active / inactive channel lists (ascending index, matches stable argsort)
    if (tid == 0) {
        int na = 0, ni = 0;
        for (int c = 0; c < 64; c++) {
            if (s_lab[c]) s_act[na++] = c;
            else          s_inact[ni++] = c;
        }
    }
    // distance matrix (diag zero), 16 entries per thread
    for (int e = tid; e < 4096; e += 256) {
        int i = e >> 6, j = e & 63;
        float dx = s_pos[i * 3 + 0] - s_pos[j * 3 + 0];
        float dy = s_pos[i * 3 + 1] - s_pos[j * 3 + 1];
        float dz = s_pos[i * 3 + 2] - s_pos[j * 3 + 2];
        float d2 = dx * dx + dy * dy + dz * dz;
        s_dist[e] = (i == j) ? 0.0f : sqrtf(d2);
    }
    __syncthreads();

    // ---- phase 2: active-row fragments into registers (L1 absorbs wave redundancy) ----
    const float4* emb4 = (const float4*)emb;
    float4 frag[4][4];
#pragma unroll
    for (int j = 0; j < 4; j++) {
        const float4* src = emb4 + (long)(b * 64 + s_act[j]) * 256;
#pragma unroll
        for (int i = 0; i < 4; i++) frag[j][i] = src[lane + 64 * i];
    }

    // ---- phase 3: stream all 64 channel rows; wave w handles rows c ≡ w (mod 4) ----
    for (int c = w; c < 64; c += 4) {
        const float4* src = emb4 + (long)(b * 64 + c) * 256;
        float4 x[4];
#pragma unroll
        for (int i = 0; i < 4; i++) x[i] = src[lane + 64 * i];
        float nsq = 0.f, d0 = 0.f, d1 = 0.f, d2 = 0.f, d3 = 0.f;
#pragma unroll
        for (int i = 0; i < 4; i++) {
            float4 xv = x[i];
            nsq += xv.x * xv.x + xv.y * xv.y + xv.z * xv.z + xv.w * xv.w;
            d0 += xv.x * frag[0][i].x + xv.y * frag[0][i].y + xv.z * frag[0][i].z + xv.w * frag[0][i].w;
            d1 += xv.x * frag[1][i].x + xv.y * frag[1][i].y + xv.z * frag[1][i].z + xv.w * frag[1][i].w;
            d2 += xv.x * frag[2][i].x + xv.y * frag[2][i].y + xv.z * frag[2][i].z + xv.w * frag[2][i].w;
            d3 += xv.x * frag[3][i].x + xv.y * frag[3][i].y + xv.z * frag[3][i].z + xv.w * frag[3][i].w;
        }
        d0 = wred(d0); d1 = wred(d1); d2 = wred(d2); d3 = wred(d3); nsq = wred(nsq);
        if (lane == 0) {
            s_dots[c][0] = d0; s_dots[c][1] = d1; s_dots[c][2] = d2; s_dots[c][3] = d3;
            s_nsq[c] = nsq;
        }
    }
    __syncthreads();

    // ---- per-wave loss terms ----
    if (w == 0) {
        // contrastive: 12 (anchor, positive) pairs, 20 negatives each
        float ce = 0.0f;
        if (lane < 12) {
            int k = lane / 3;
            int r = lane % 3;
            int m = r + ((r >= k) ? 1 : 0); // r-th column != k
            float nk = fmaxf(sqrtf(s_nsq[s_act[k]]), 1e-12f);
            float nm = fmaxf(sqrtf(s_nsq[s_act[m]]), 1e-12f);
            float posv = s_dots[s_act[k]][m] / (nk * nm) * INV_TEMP;
            float neg[20];
            float mx = posv;
            int base = r * 20;
#pragma unroll
            for (int t = 0; t < 20; t++) {
                int c = s_inact[base + t];
                float nc = fmaxf(sqrtf(s_nsq[c]), 1e-12f);
                neg[t] = s_dots[c][k] / (nk * nc) * INV_TEMP;
                mx = fmaxf(mx, neg[t]);
            }
            float sum = __expf(posv - mx);
#pragma unroll
            for (int t = 0; t < 20; t++) sum += __expf(neg[t] - mx);
            ce = logf(sum) + mx - posv;
        }
        ce = wred(ce);
        if (lane == 0) s_part[0] = ce;
    } else if (w == 1) {
        // score (BCE), margin, top-k
        float p = s_p[lane];
        int   l = s_lab[lane];
        float sc = l ? -logf(p) : -log1pf(-p);
        sc = wred(sc);
        float s1 = wred(l ? p : 0.0f); // sum over active
        float s2 = wred(p);            // total sum
        // top-4 via 4 argmax rounds (tie -> lower index, matches lax.top_k)
        float pv = s_p[lane];
        int inter = 0;
#pragma unroll
        for (int it = 0; it < 4; it++) {
            float v = pv;
            int   ix = lane;
#pragma unroll
            for (int off = 32; off > 0; off >>= 1) {
                float ov = __shfl_xor(v, off, 64);
                int   oi = __shfl_xor(ix, off, 64);
                if (ov > v || (ov == v && oi < ix)) { v = ov; ix = oi; }
            }
            if (lane == ix) pv = -1e30f;
            if (s_lab[ix]) inter++;
        }
        if (lane == 0) {
            s_part[1] = sc;
            float am = s1 * (1.0f / 4.0f);
            float im = (s2 - s1) * (1.0f / 60.0f);
            s_part[2] = fmaxf(MARGIN_C - (am - im), 0.0f);
            float fi = (float)inter;
            float un = (float)(8 - inter);
            s_part[3] = 1.0f - fi / (un + 1e-8f);
        }
    } else if (w == 2) {
        // spatial: pair_sum = sum_{i,j} m_i m_j dist[i][j]
        bool  mj = s_p[lane] > 0.5f;
        float tj = 0.0f;
        for (int i = 0; i < 64; i++) {
            tj += (s_p[i] > 0.5f) ? s_dist[i * 64 + lane] : 0.0f;
        }
        float pair = wred(mj ? tj : 0.0f);
        unsigned long long bal = __ballot(mj);
        int nm = __popcll(bal);
        if (lane == 0) {
            s_part[4] = (nm >= 2) ? pair / fmaxf((float)nm * (float)(nm - 1), 1.0f) : 0.0f;
        }
    } else {
        // network coherence: p^T W p
        float tj = 0.0f;
        for (int i = 0; i < 64; i++) tj += s_p[i] * conn[i * 64 + lane];
        float coh = wred(tj * s_p[lane]);
        if (lane == 0) s_part[5] = -coh * (1.0f / 4096.0f);
    }
    __syncthreads();

    if (tid == 0) {
        float contrib = 3.0f * s_part[1] * (1.0f / 64.0f)  // score (per-row mean over C)
                      + s_part[2]                           // margin
                      + 2.0f * s_part[3]                    // topk
                      + s_part[0] * (1.0f / 12.0f)          // contrastive
                      + 0.5f * s_part[4]                    // spatial
                      + 0.5f * s_part[5];                   // network
        atomicAdd(out, contrib * (1.0f / (float)B_N));
    }
}

extern "C" void kernel_launch(void* const* d_in, const int* in_sizes, int n_in,
                              void* d_out, int out_size, void* d_ws, size_t ws_size,
                              hipStream_t stream) {
    const float* pred = (const float*)d_in[0];
    const int*   lab  = (const int*)d_in[1];
    const float* emb  = (const float*)d_in[2];
    const float* cpos = (const float*)d_in[3];
    const float* conn = (const float*)d_in[4];
    float* out = (float*)d_out;

    zero_out_kernel<<<1, 64, 0, stream>>>(out);
    loss_kernel<<<B_N, 256, 0, stream>>>(pred, lab, emb, cpos, conn, out);
}